// Round 15
// baseline (256.742 us; speedup 1.0000x reference)
//
#include <hip/hip_runtime.h>
#include <math.h>

#define B_ 4096
#define D_ 512
#define G_ 128
#define N_ (G_*G_)        // 16384
#define THR_ 0.95f
#define IMAX_ 0x7FFFFFFF

typedef float f32x4 __attribute__((ext_vector_type(4)));
typedef _Float16 half8 __attribute__((ext_vector_type(8)));

#define PKID_ ((0xFF800000ull << 32) | 0x7FFFFFFFull)   // packed(+inf, IMAX)

// ---------------- fused prep: A split + W split/wnorm + zero count/sum_min/rowmins ----------------
__global__ __launch_bounds__(256) void prep_kernel(
    const float* __restrict__ A, const float* __restrict__ W,
    _Float16* __restrict__ Ahi, _Float16* __restrict__ Whi,
    float* __restrict__ wnorm,
    float* __restrict__ count, float* __restrict__ sum_min,
    unsigned long long* __restrict__ rowb, unsigned long long* __restrict__ rowc)
{
    const int blk = blockIdx.x, tid = threadIdx.x;
    if (blk < 2048) {
        int i = blk * 256 + tid;
        float4 v = ((const float4*)A)[i];
        float vv[4] = {v.x, v.y, v.z, v.w};
        union { _Float16 h[4]; uint64_t u64; } H;
        #pragma unroll
        for (int j = 0; j < 4; j++) H.h[j] = (_Float16)vv[j];
        ((uint64_t*)Ahi)[i] = H.u64;
    } else if (blk < 6144) {
        int n = (blk - 2048) * 4 + (tid >> 6);
        int t = tid & 63;
        const float* row = W + (size_t)n * D_;
        float4 a = ((const float4*)row)[t];
        float4 b = ((const float4*)row)[t + 64];
        float av[4] = {a.x, a.y, a.z, a.w}, bv[4] = {b.x, b.y, b.z, b.w};
        union { _Float16 h[4]; uint64_t u64; } Ha, Hb;
        #pragma unroll
        for (int j = 0; j < 4; j++) { Ha.h[j] = (_Float16)av[j]; Hb.h[j] = (_Float16)bv[j]; }
        ((uint64_t*)(Whi + (size_t)n * D_))[t]       = Ha.u64;
        ((uint64_t*)(Whi + (size_t)n * D_ + 256))[t] = Hb.u64;
        float s = a.x*a.x + a.y*a.y + a.z*a.z + a.w*a.w
                + b.x*b.x + b.y*b.y + b.z*b.z + b.w*b.w;
        #pragma unroll
        for (int off = 32; off > 0; off >>= 1) s += __shfl_down(s, off, 64);
        if (t == 0) wnorm[n] = s;
    } else if (blk < 6160) {
        if (blk == 6144 && tid < 65) sum_min[tid] = 0.f;
        int j = (blk - 6144) * 256 + tid;              // 4096 float4 = count
        float4 z = {0.f, 0.f, 0.f, 0.f};
        ((float4*)count)[j] = z;
    } else if (blk == 6160) {
        #pragma unroll
        for (int k = 0; k < 16; k++) rowb[tid + k * 256] = PKID_;
    } else {
        #pragma unroll
        for (int k = 0; k < 16; k++) rowc[tid + k * 256] = PKID_;
    }
}

// ---------------- packed (value,index) helpers for argmin ----------------
__device__ __forceinline__ unsigned long long packmin(float v, int n) {
    unsigned u = __float_as_uint(v);
    u ^= (u & 0x80000000u) ? 0xFFFFFFFFu : 0x80000000u;
    return ((unsigned long long)u << 32) | (unsigned)n;
}
__device__ __forceinline__ void unpackmin(unsigned long long pkt, float* v, int* n) {
    unsigned u = (unsigned)(pkt >> 32);
    u = (u & 0x80000000u) ? (u ^ 0x80000000u) : ~u;
    *v = __uint_as_float(u);
    *n = (int)(unsigned)pkt;
}

// ---------------- MFMA score GEMM: 256x256 tile, 8 waves, r7/r11-proven 4-phase ----------------
// Verified control: 103-107us, MfmaUtil ~27%, absmax 0.546875. r5/r12/r13 falsified the
// alternatives — this structure is the plateau; do not touch the GEMM loop.
// r15: per-row argmin published via packed-u64 atomicMin (lex-min == tree-min, bit-exact);
// partial arrays and reduce-side gather/butterfly eliminated.

#define PH_WAIT_(N) asm volatile("s_waitcnt vmcnt(" #N ")" ::: "memory")
#define PH_WAIT(N) PH_WAIT_(N)
#define WAITLGKM0 asm volatile("s_waitcnt lgkmcnt(0)" ::: "memory")
#define SBAR __builtin_amdgcn_s_barrier()
#define SCHED0 __builtin_amdgcn_sched_barrier(0)
#define PRIO1 __builtin_amdgcn_s_setprio(1)
#define PRIO0 __builtin_amdgcn_s_setprio(0)

#define STAGE_HALF(GBASE, LOFF, TAU, H) do { \
    __builtin_amdgcn_global_load_lds( \
        (const __attribute__((address_space(1))) void*)((GBASE) + (size_t)(H) * (128 * D_) + (TAU) * 64 + srcoff0), \
        (__attribute__((address_space(3))) void*)(smem + (LOFF) + (((TAU) & 1) << 15) + ((H) << 14) + ldsoff0), 16, 0, 0); \
    __builtin_amdgcn_global_load_lds( \
        (const __attribute__((address_space(1))) void*)((GBASE) + (size_t)(H) * (128 * D_) + (TAU) * 64 + srcoff1), \
        (__attribute__((address_space(3))) void*)(smem + (LOFF) + (((TAU) & 1) << 15) + ((H) << 14) + ldsoff1), 16, 0, 0); \
} while (0)

#define TILE(TAU, S1, S3, S4, DO_W, VM4) do { \
    half8 af[4][2], bl[2][2], bh[2][2]; \
    _Pragma("unroll") for (int mi = 0; mi < 4; mi++) { \
        af[mi][0] = *(const half8*)(smem + (((TAU) & 1) << 15) + sA + mi * 2048 + swz0); \
        af[mi][1] = *(const half8*)(smem + (((TAU) & 1) << 15) + sA + mi * 2048 + swz1); } \
    _Pragma("unroll") for (int ni = 0; ni < 2; ni++) { \
        bl[ni][0] = *(const half8*)(smem + 65536 + (((TAU) & 1) << 15) + sB + ni * 2048 + swz0); \
        bl[ni][1] = *(const half8*)(smem + 65536 + (((TAU) & 1) << 15) + sB + ni * 2048 + swz1); } \
    if (S1) STAGE_HALF(Abase, 0, (TAU) + 1, 1); \
    SBAR; WAITLGKM0; SCHED0; PRIO1; \
    _Pragma("unroll") for (int mi = 0; mi < 4; mi++) \
      _Pragma("unroll") for (int ni = 0; ni < 2; ni++) { \
        acc[mi][ni] = __builtin_amdgcn_mfma_f32_16x16x32_f16(af[mi][0], bl[ni][0], acc[mi][ni], 0, 0, 0); \
        acc[mi][ni] = __builtin_amdgcn_mfma_f32_16x16x32_f16(af[mi][1], bl[ni][1], acc[mi][ni], 0, 0, 0); } \
    PRIO0; SCHED0; SBAR; \
    _Pragma("unroll") for (int ni = 0; ni < 2; ni++) { \
        bh[ni][0] = *(const half8*)(smem + 65536 + (((TAU) & 1) << 15) + sB + (ni + 2) * 2048 + swz0); \
        bh[ni][1] = *(const half8*)(smem + 65536 + (((TAU) & 1) << 15) + sB + (ni + 2) * 2048 + swz1); } \
    SBAR; WAITLGKM0; SCHED0; PRIO1; \
    _Pragma("unroll") for (int mi = 0; mi < 4; mi++) \
      _Pragma("unroll") for (int ni = 0; ni < 2; ni++) { \
        acc[mi][ni + 2] = __builtin_amdgcn_mfma_f32_16x16x32_f16(af[mi][0], bh[ni][0], acc[mi][ni + 2], 0, 0, 0); \
        acc[mi][ni + 2] = __builtin_amdgcn_mfma_f32_16x16x32_f16(af[mi][1], bh[ni][1], acc[mi][ni + 2], 0, 0, 0); } \
    PRIO0; SCHED0; SBAR; \
    _Pragma("unroll") for (int mi = 0; mi < 4; mi++) { \
        af[mi][0] = *(const half8*)(smem + (((TAU) & 1) << 15) + sA + (mi + 4) * 2048 + swz0); \
        af[mi][1] = *(const half8*)(smem + (((TAU) & 1) << 15) + sA + (mi + 4) * 2048 + swz1); } \
    if (S3) STAGE_HALF(Wbase, 65536, (TAU) + 2, 0); \
    SBAR; WAITLGKM0; SCHED0; PRIO1; \
    _Pragma("unroll") for (int mi = 0; mi < 4; mi++) \
      _Pragma("unroll") for (int ni = 0; ni < 2; ni++) { \
        acc[mi + 4][ni + 2] = __builtin_amdgcn_mfma_f32_16x16x32_f16(af[mi][0], bh[ni][0], acc[mi + 4][ni + 2], 0, 0, 0); \
        acc[mi + 4][ni + 2] = __builtin_amdgcn_mfma_f32_16x16x32_f16(af[mi][1], bh[ni][1], acc[mi + 4][ni + 2], 0, 0, 0); } \
    PRIO0; SCHED0; SBAR; \
    if (S4) { STAGE_HALF(Abase, 0, (TAU) + 2, 0); STAGE_HALF(Wbase, 65536, (TAU) + 2, 1); } \
    if (DO_W) PH_WAIT(VM4); \
    SBAR; PRIO1; \
    _Pragma("unroll") for (int mi = 0; mi < 4; mi++) \
      _Pragma("unroll") for (int ni = 0; ni < 2; ni++) { \
        acc[mi + 4][ni] = __builtin_amdgcn_mfma_f32_16x16x32_f16(af[mi][0], bl[ni][0], acc[mi + 4][ni], 0, 0, 0); \
        acc[mi + 4][ni] = __builtin_amdgcn_mfma_f32_16x16x32_f16(af[mi][1], bl[ni][1], acc[mi + 4][ni], 0, 0, 0); } \
    PRIO0; SCHED0; SBAR; \
} while (0)

__global__ __launch_bounds__(512, 2) void score_mfma_kernel(
    const _Float16* __restrict__ Ah, const _Float16* __restrict__ Wh,
    const float* __restrict__ wnorm,
    const int* __restrict__ labels, const int* __restrict__ clabels,
    unsigned long long* __restrict__ rowb, unsigned long long* __restrict__ rowc,
    float* __restrict__ S, int zeroS)
{
    __shared__ __align__(16) char smem[131072];  // A: 2x32KB @0, B: 2x32KB @64KB

    const int tid  = threadIdx.x;
    const int lane = tid & 63;
    const int wave = tid >> 6;
    const int wm = wave >> 2, wn = wave & 3;     // 2M x 4N wave grid; 128x64 per wave
    const int c = lane & 15, quad = lane >> 4;

    const int o = blockIdx.x;
    const int xcd = o & 7, idx = o >> 3;
    const int ntile = (xcd << 3) | (idx & 7);
    const int mtile = idx >> 3;
    const int m0 = mtile * 256, n0 = ntile * 256;

    const _Float16* Abase = Ah + (size_t)m0 * D_;
    const _Float16* Wbase = Wh + (size_t)n0 * D_;

    const int i0 = tid, i1 = 512 + tid;
    const int rl0 = i0 >> 3, sl0 = i0 & 7, rl1 = i1 >> 3, sl1 = i1 & 7;
    const size_t srcoff0 = (size_t)rl0 * D_ + ((sl0 ^ (rl0 & 7)) << 3);
    const size_t srcoff1 = (size_t)rl1 * D_ + ((sl1 ^ (rl1 & 7)) << 3);
    const int ldsoff0 = i0 << 4, ldsoff1 = i1 << 4;

    const int sA = (wm * 128 + c) * 128;
    const int sB = (wn * 64 + c) * 128;
    const int swz0 = ((0 * 4 + quad) ^ (c & 7)) << 4;   // kk=0
    const int swz1 = ((1 * 4 + quad) ^ (c & 7)) << 4;   // kk=1

    f32x4 acc[8][4];
    #pragma unroll
    for (int i = 0; i < 8; i++)
        #pragma unroll
        for (int j = 0; j < 4; j++)
            acc[i][j] = (f32x4){0.f, 0.f, 0.f, 0.f};

    STAGE_HALF(Abase, 0, 0, 0);
    STAGE_HALF(Wbase, 65536, 0, 0);
    STAGE_HALF(Wbase, 65536, 0, 1);
    STAGE_HALF(Abase, 0, 0, 1);
    STAGE_HALF(Abase, 0, 1, 0);
    STAGE_HALF(Wbase, 65536, 1, 0);
    STAGE_HALF(Wbase, 65536, 1, 1);
    PH_WAIT(6); SBAR;

    TILE(0, 1, 1, 1, 1, 6);
    TILE(1, 1, 1, 1, 1, 6);
    TILE(2, 1, 1, 1, 1, 6);
    TILE(3, 1, 1, 1, 1, 6);
    TILE(4, 1, 1, 1, 1, 6);
    TILE(5, 1, 1, 1, 1, 6);
    TILE(6, 1, 0, 0, 1, 0);
    TILE(7, 0, 0, 0, 0, 0);

    __syncthreads();   // GEMM done; reuse smem as [256][64] u64 candidate table

    const unsigned long long ID = PKID_;
    float wnl[4]; int cll[4];
    #pragma unroll
    for (int ni = 0; ni < 4; ni++) {
        int n = n0 + wn * 64 + ni * 16 + c;
        wnl[ni] = wnorm[n];
        cll[ni] = clabels[n];
    }

    unsigned long long (*tbl)[64] = (unsigned long long (*)[64])smem;  // 128KB exactly
    unsigned long long cbst[8][4];

    #pragma unroll
    for (int mi = 0; mi < 8; mi++) {
        #pragma unroll
        for (int r = 0; r < 4; r++) {
            int rowl = wm * 128 + mi * 16 + quad * 4 + r;   // 0..255 in block
            int lb = labels[m0 + rowl];
            unsigned long long bb = ID, cb = ID;
            #pragma unroll
            for (int ni = 0; ni < 4; ni++) {
                float s = fmaf(-2.f, acc[mi][ni][r], wnl[ni]);
                unsigned long long pk = packmin(s, n0 + wn * 64 + ni * 16 + c);
                bb = bb < pk ? bb : pk;
                if (cll[ni] == lb) cb = cb < pk ? cb : pk;
            }
            tbl[rowl][(wn * 16 + c) ^ (rowl & 15)] = bb;   // XOR slot: caps conflicts 4-way
            cbst[mi][r] = cb;
        }
    }
    __syncthreads();
    if (tid < 256) {
        int row = tid;
        unsigned long long m = ID;
        #pragma unroll
        for (int j = 0; j < 64; j++) {
            unsigned long long v = tbl[row][j ^ (row & 15)];
            m = m < v ? m : v;
        }
        atomicMin(&rowb[m0 + row], m);   // packed lex-min: bit-identical to tree-min
    }
    __syncthreads();
    #pragma unroll
    for (int mi = 0; mi < 8; mi++)
        #pragma unroll
        for (int r = 0; r < 4; r++) {
            int rowl = wm * 128 + mi * 16 + quad * 4 + r;
            tbl[rowl][(wn * 16 + c) ^ (rowl & 15)] = cbst[mi][r];
        }
    __syncthreads();
    if (tid < 256) {
        int row = tid;
        unsigned long long m = ID;
        #pragma unroll
        for (int j = 0; j < 64; j++) {
            unsigned long long v = tbl[row][j ^ (row & 15)];
            m = m < v ? m : v;
        }
        atomicMin(&rowc[m0 + row], m);
    }

    // zero this block's 1/1024 slice of S (fused-S layout only; non-aliased).
    if (zeroS) {
        const float4 z = {0.f, 0.f, 0.f, 0.f};
        float4* Sz = (float4*)(S + (size_t)o * 8192);
        #pragma unroll
        for (int k = 0; k < 4; k++)
            Sz[k * 512 + tid] = z;
    }
}

// ---------------- reduce: wave-autonomous per row (minima already global) + scatter ----------------
// Row minima come pre-reduced from score's atomicMin -> no gather, no argmin butterfly,
// no LDS, no syncthreads. Per wave: uniform loads of rowb/rowc, xs butterfly, out0 write,
// 8 coalesced 256B atomic scatter rounds.
__global__ __launch_bounds__(256) void reduce_kernel(
    const float* __restrict__ A, const float* __restrict__ W,
    const float* __restrict__ crel,
    const unsigned long long* __restrict__ rowb,
    const unsigned long long* __restrict__ rowc,
    float* __restrict__ sum_min, float* __restrict__ out0,
    float* __restrict__ S, float* __restrict__ count)
{
    const int b = blockIdx.x * 4 + (threadIdx.x >> 6);
    const int l = threadIdx.x & 63;

    float bv; int bn; unpackmin(rowb[b], &bv, &bn);
    float cv; int cn; unpackmin(rowc[b], &cv, &cn);

    const float* arow = A + (size_t)b * D_;
    float4 xa = ((const float4*)arow)[l];
    float4 xb = ((const float4*)arow)[l + 64];
    float xs = xa.x*xa.x + xa.y*xa.y + xa.z*xa.z + xa.w*xa.w
             + xb.x*xb.x + xb.y*xb.y + xb.z*xb.z + xb.w*xb.w;
    #pragma unroll
    for (int off = 1; off < 64; off <<= 1) xs += __shfl_xor(xs, off, 64);

    if (l == 0) {
        float md = xs + bv;
        if (md < 0.f) md = 0.f;
        atomicAdd(&sum_min[b & 63], md);
        atomicAdd(&count[bn], 1.0f);
    }

    float r = crel[cn] / 100.0f;
    float sc = (r >= THR_) ? 0.01f * r : 0.f;
    const float* wrow = W + (size_t)cn * D_;
    float4 wa = ((const float4*)wrow)[l];
    float4 wb = ((const float4*)wrow)[l + 64];
    float4 oa, ob4;
    oa.x = sc * (wa.x - xa.x); oa.y = sc * (wa.y - xa.y);
    oa.z = sc * (wa.z - xa.z); oa.w = sc * (wa.w - xa.w);
    ob4.x = sc * (wb.x - xb.x); ob4.y = sc * (wb.y - xb.y);
    ob4.z = sc * (wb.z - xb.z); ob4.w = sc * (wb.w - xb.w);
    float* orow = out0 + (size_t)b * D_;
    ((float4*)orow)[l]      = oa;
    ((float4*)orow)[l + 64] = ob4;

    float* Sr = S + (size_t)bn * D_;
    #pragma unroll
    for (int k = 0; k < 8; k++)
        atomicAdd(&Sr[k * 64 + l], arow[k * 64 + l]);
}

// ---------------- final: out1 = som + stencil(S) - som*denom (gated); denom inlined ----------------
__global__ __launch_bounds__(256) void final_kernel(
    const float* __restrict__ som, const float* __restrict__ S,
    const float* __restrict__ count, const float* __restrict__ sum_min,
    const int* __restrict__ epoch_p, const int* __restrict__ maxep_p,
    float* __restrict__ out1)
{
    __shared__ float gsum;
    if (threadIdx.x < 64) {
        float s = sum_min[threadIdx.x];
        #pragma unroll
        for (int off = 32; off > 0; off >>= 1) s += __shfl_xor(s, off, 64);
        if (threadIdx.x == 0) gsum = s;
    }
    __syncthreads();

    const int o = blockIdx.x;                      // 8192 blocks
    const int vb = ((o & 7) << 10) | (o >> 3);     // xcd*1024 + idx  (bijective)
    size_t i4 = (size_t)vb * 256 + threadIdx.x;
    int n = (int)(i4 >> 7);          // 128 float4 per cell row
    int d4 = (int)(i4 & 127);
    float4 s = ((const float4*)som)[i4];
    bool gate = gsum > 1e-4f * (float)B_;   // mean(min_dists) > 1e-4
    float4 ov = s;
    if (gate) {
        int ep = epoch_p[0], me = maxep_p[0];
        float progress = (me > 0) ? (float)(me - ep) / (float)me : 0.f;
        progress = fminf(fmaxf(progress, 0.f), 1.f);
        float p2 = progress * progress;
        int ctx = (int)(p2 * p2 * 2.0f);
        float lr = 0.05f + progress * 0.15f;

        int i = n / G_, j = n % G_;
        float4 nu = {0.f, 0.f, 0.f, 0.f};
        float dn = 0.f;
        for (int di = -ctx; di <= ctx; di++) {
            int ia = i - di; if (ia < 0 || ia >= G_) continue;
            for (int dj = -ctx; dj <= ctx; dj++) {
                int jb = j - dj; if (jb < 0 || jb >= G_) continue;
                int ad = abs(di), aj = abs(dj);
                int cheb = ad > aj ? ad : aj;
                float coef = ldexpf(lr, -cheb);
                float4 t4 = ((const float4*)S)[(size_t)(jb * G_ + ia) * 128 + d4];
                nu.x += coef * t4.x; nu.y += coef * t4.y;
                nu.z += coef * t4.z; nu.w += coef * t4.w;
                dn += coef * count[jb * G_ + ia];
            }
        }
        ov.x = s.x + nu.x - s.x * dn;
        ov.y = s.y + nu.y - s.y * dn;
        ov.z = s.z + nu.z - s.z * dn;
        ov.w = s.w + nu.w - s.w * dn;
    }
    ((float4*)out1)[i4] = ov;
}

extern "C" void kernel_launch(void* const* d_in, const int* in_sizes, int n_in,
                              void* d_out, int out_size, void* d_ws, size_t ws_size,
                              hipStream_t stream) {
    const float* A   = (const float*)d_in[0];   // activations [B][D]
    const int*   lab = (const int*)d_in[1];     // labels [B]
    const float* W   = (const float*)d_in[2];   // som_vectors [G*G][D]
    const int*   cl  = (const int*)d_in[3];     // cell_labels [G*G]
    const float* cr  = (const float*)d_in[4];   // cell_reliability [G*G]
    const int*   ep  = (const int*)d_in[5];     // epoch
    const int*   me  = (const int*)d_in[6];     // max_epochs

    float* out0 = (float*)d_out;                // som_errors [B][D]
    float* out1 = out0 + (size_t)B_ * D_;       // new_som [G*G][D]

    const size_t MB = 1024 * 1024;
    uint8_t* w = (uint8_t*)d_ws;
    _Float16* Ahi  = (_Float16*)(w);                    //  4 MB
    _Float16* Whi  = (_Float16*)(w + 4 * MB);           // 16 MB
    unsigned long long* rowb = (unsigned long long*)(w + 32 * MB);   // 32 KB
    unsigned long long* rowc = (unsigned long long*)(w + 33 * MB);   // 32 KB
    float* wnorm   = (float*)(w + 40 * MB);             // 64 KB
    float* count   = (float*)(w + 40 * MB + 128 * 1024);// 64 KB
    float* sum_min = (float*)(w + 40 * MB + 256 * 1024);// 65 floats: 64 buckets + total

    // S: non-aliased at [48,80) MB if workspace allows (zeroed in score epilogue);
    // else aliases the dead f16 region and is zeroed by a stream-ordered memset.
    const int fusedS = (ws_size >= 80 * MB) ? 1 : 0;
    float* S = fusedS ? (float*)(w + 48 * MB) : (float*)w;

    prep_kernel<<<6162, 256, 0, stream>>>(A, W, Ahi, Whi, wnorm, count, sum_min,
                                          rowb, rowc);

    score_mfma_kernel<<<dim3((B_ / 256) * (N_ / 256)), 512, 0, stream>>>(
        Ahi, Whi, wnorm, lab, cl, rowb, rowc, S, fusedS);

    if (!fusedS)
        hipMemsetAsync(S, 0, (size_t)N_ * D_ * sizeof(float), stream);

    reduce_kernel<<<B_ / 4, 256, 0, stream>>>(A, W, cr, rowb, rowc,
                                              sum_min, out0, S, count);

    final_kernel<<<(N_ * D_ / 4) / 256, 256, 0, stream>>>(
        W, S, count, sum_min, ep, me, out1);
}

// Round 16
// 251.843 us; speedup vs baseline: 1.0195x; 1.0195x over previous
//
#include <hip/hip_runtime.h>
#include <math.h>

#define B_ 4096
#define D_ 512
#define G_ 128
#define N_ (G_*G_)        // 16384
#define THR_ 0.95f
#define IMAX_ 0x7FFFFFFF

typedef float f32x4 __attribute__((ext_vector_type(4)));
typedef _Float16 half8 __attribute__((ext_vector_type(8)));

#define PKID_ ((0xFF800000ull << 32) | 0x7FFFFFFFull)   // packed(+inf, IMAX)

// ---------------- fused prep: A split + W split/wnorm + zero count/sum_min/rowmins ----------------
__global__ __launch_bounds__(256) void prep_kernel(
    const float* __restrict__ A, const float* __restrict__ W,
    _Float16* __restrict__ Ahi, _Float16* __restrict__ Whi,
    float* __restrict__ wnorm,
    float* __restrict__ count, float* __restrict__ sum_min,
    unsigned long long* __restrict__ rowb, unsigned long long* __restrict__ rowc)
{
    const int blk = blockIdx.x, tid = threadIdx.x;
    if (blk < 2048) {
        int i = blk * 256 + tid;
        float4 v = ((const float4*)A)[i];
        float vv[4] = {v.x, v.y, v.z, v.w};
        union { _Float16 h[4]; uint64_t u64; } H;
        #pragma unroll
        for (int j = 0; j < 4; j++) H.h[j] = (_Float16)vv[j];
        ((uint64_t*)Ahi)[i] = H.u64;
    } else if (blk < 6144) {
        int n = (blk - 2048) * 4 + (tid >> 6);
        int t = tid & 63;
        const float* row = W + (size_t)n * D_;
        float4 a = ((const float4*)row)[t];
        float4 b = ((const float4*)row)[t + 64];
        float av[4] = {a.x, a.y, a.z, a.w}, bv[4] = {b.x, b.y, b.z, b.w};
        union { _Float16 h[4]; uint64_t u64; } Ha, Hb;
        #pragma unroll
        for (int j = 0; j < 4; j++) { Ha.h[j] = (_Float16)av[j]; Hb.h[j] = (_Float16)bv[j]; }
        ((uint64_t*)(Whi + (size_t)n * D_))[t]       = Ha.u64;
        ((uint64_t*)(Whi + (size_t)n * D_ + 256))[t] = Hb.u64;
        float s = a.x*a.x + a.y*a.y + a.z*a.z + a.w*a.w
                + b.x*b.x + b.y*b.y + b.z*b.z + b.w*b.w;
        #pragma unroll
        for (int off = 32; off > 0; off >>= 1) s += __shfl_down(s, off, 64);
        if (t == 0) wnorm[n] = s;
    } else if (blk < 6160) {
        if (blk == 6144 && tid < 65) sum_min[tid] = 0.f;
        int j = (blk - 6144) * 256 + tid;              // 4096 float4 = count
        float4 z = {0.f, 0.f, 0.f, 0.f};
        ((float4*)count)[j] = z;
    } else if (blk == 6160) {
        #pragma unroll
        for (int k = 0; k < 16; k++) rowb[tid + k * 256] = PKID_;
    } else {
        #pragma unroll
        for (int k = 0; k < 16; k++) rowc[tid + k * 256] = PKID_;
    }
}

// ---------------- packed (value,index) helpers for argmin ----------------
__device__ __forceinline__ unsigned long long packmin(float v, int n) {
    unsigned u = __float_as_uint(v);
    u ^= (u & 0x80000000u) ? 0xFFFFFFFFu : 0x80000000u;
    return ((unsigned long long)u << 32) | (unsigned)n;
}
__device__ __forceinline__ void unpackmin(unsigned long long pkt, float* v, int* n) {
    unsigned u = (unsigned)(pkt >> 32);
    u = (u & 0x80000000u) ? (u ^ 0x80000000u) : ~u;
    *v = __uint_as_float(u);
    *n = (int)(unsigned)pkt;
}

// ---------------- MFMA score GEMM: 256x256 tile, 8 waves, r7/r11-proven 4-phase ----------------
// Verified control: 103-107us, MfmaUtil ~27%, absmax 0.546875. r5/r12/r13 falsified the
// alternatives — this structure is the plateau; do not touch the GEMM loop.

#define PH_WAIT_(N) asm volatile("s_waitcnt vmcnt(" #N ")" ::: "memory")
#define PH_WAIT(N) PH_WAIT_(N)
#define WAITLGKM0 asm volatile("s_waitcnt lgkmcnt(0)" ::: "memory")
#define SBAR __builtin_amdgcn_s_barrier()
#define SCHED0 __builtin_amdgcn_sched_barrier(0)
#define PRIO1 __builtin_amdgcn_s_setprio(1)
#define PRIO0 __builtin_amdgcn_s_setprio(0)

#define STAGE_HALF(GBASE, LOFF, TAU, H) do { \
    __builtin_amdgcn_global_load_lds( \
        (const __attribute__((address_space(1))) void*)((GBASE) + (size_t)(H) * (128 * D_) + (TAU) * 64 + srcoff0), \
        (__attribute__((address_space(3))) void*)(smem + (LOFF) + (((TAU) & 1) << 15) + ((H) << 14) + ldsoff0), 16, 0, 0); \
    __builtin_amdgcn_global_load_lds( \
        (const __attribute__((address_space(1))) void*)((GBASE) + (size_t)(H) * (128 * D_) + (TAU) * 64 + srcoff1), \
        (__attribute__((address_space(3))) void*)(smem + (LOFF) + (((TAU) & 1) << 15) + ((H) << 14) + ldsoff1), 16, 0, 0); \
} while (0)

#define TILE(TAU, S1, S3, S4, DO_W, VM4) do { \
    half8 af[4][2], bl[2][2], bh[2][2]; \
    _Pragma("unroll") for (int mi = 0; mi < 4; mi++) { \
        af[mi][0] = *(const half8*)(smem + (((TAU) & 1) << 15) + sA + mi * 2048 + swz0); \
        af[mi][1] = *(const half8*)(smem + (((TAU) & 1) << 15) + sA + mi * 2048 + swz1); } \
    _Pragma("unroll") for (int ni = 0; ni < 2; ni++) { \
        bl[ni][0] = *(const half8*)(smem + 65536 + (((TAU) & 1) << 15) + sB + ni * 2048 + swz0); \
        bl[ni][1] = *(const half8*)(smem + 65536 + (((TAU) & 1) << 15) + sB + ni * 2048 + swz1); } \
    if (S1) STAGE_HALF(Abase, 0, (TAU) + 1, 1); \
    SBAR; WAITLGKM0; SCHED0; PRIO1; \
    _Pragma("unroll") for (int mi = 0; mi < 4; mi++) \
      _Pragma("unroll") for (int ni = 0; ni < 2; ni++) { \
        acc[mi][ni] = __builtin_amdgcn_mfma_f32_16x16x32_f16(af[mi][0], bl[ni][0], acc[mi][ni], 0, 0, 0); \
        acc[mi][ni] = __builtin_amdgcn_mfma_f32_16x16x32_f16(af[mi][1], bl[ni][1], acc[mi][ni], 0, 0, 0); } \
    PRIO0; SCHED0; SBAR; \
    _Pragma("unroll") for (int ni = 0; ni < 2; ni++) { \
        bh[ni][0] = *(const half8*)(smem + 65536 + (((TAU) & 1) << 15) + sB + (ni + 2) * 2048 + swz0); \
        bh[ni][1] = *(const half8*)(smem + 65536 + (((TAU) & 1) << 15) + sB + (ni + 2) * 2048 + swz1); } \
    SBAR; WAITLGKM0; SCHED0; PRIO1; \
    _Pragma("unroll") for (int mi = 0; mi < 4; mi++) \
      _Pragma("unroll") for (int ni = 0; ni < 2; ni++) { \
        acc[mi][ni + 2] = __builtin_amdgcn_mfma_f32_16x16x32_f16(af[mi][0], bh[ni][0], acc[mi][ni + 2], 0, 0, 0); \
        acc[mi][ni + 2] = __builtin_amdgcn_mfma_f32_16x16x32_f16(af[mi][1], bh[ni][1], acc[mi][ni + 2], 0, 0, 0); } \
    PRIO0; SCHED0; SBAR; \
    _Pragma("unroll") for (int mi = 0; mi < 4; mi++) { \
        af[mi][0] = *(const half8*)(smem + (((TAU) & 1) << 15) + sA + (mi + 4) * 2048 + swz0); \
        af[mi][1] = *(const half8*)(smem + (((TAU) & 1) << 15) + sA + (mi + 4) * 2048 + swz1); } \
    if (S3) STAGE_HALF(Wbase, 65536, (TAU) + 2, 0); \
    SBAR; WAITLGKM0; SCHED0; PRIO1; \
    _Pragma("unroll") for (int mi = 0; mi < 4; mi++) \
      _Pragma("unroll") for (int ni = 0; ni < 2; ni++) { \
        acc[mi + 4][ni + 2] = __builtin_amdgcn_mfma_f32_16x16x32_f16(af[mi][0], bh[ni][0], acc[mi + 4][ni + 2], 0, 0, 0); \
        acc[mi + 4][ni + 2] = __builtin_amdgcn_mfma_f32_16x16x32_f16(af[mi][1], bh[ni][1], acc[mi + 4][ni + 2], 0, 0, 0); } \
    PRIO0; SCHED0; SBAR; \
    if (S4) { STAGE_HALF(Abase, 0, (TAU) + 2, 0); STAGE_HALF(Wbase, 65536, (TAU) + 2, 1); } \
    if (DO_W) PH_WAIT(VM4); \
    SBAR; PRIO1; \
    _Pragma("unroll") for (int mi = 0; mi < 4; mi++) \
      _Pragma("unroll") for (int ni = 0; ni < 2; ni++) { \
        acc[mi + 4][ni] = __builtin_amdgcn_mfma_f32_16x16x32_f16(af[mi][0], bl[ni][0], acc[mi + 4][ni], 0, 0, 0); \
        acc[mi + 4][ni] = __builtin_amdgcn_mfma_f32_16x16x32_f16(af[mi][1], bl[ni][1], acc[mi + 4][ni], 0, 0, 0); } \
    PRIO0; SCHED0; SBAR; \
} while (0)

__global__ __launch_bounds__(512, 2) void score_mfma_kernel(
    const _Float16* __restrict__ Ah, const _Float16* __restrict__ Wh,
    const float* __restrict__ wnorm,
    const int* __restrict__ labels, const int* __restrict__ clabels,
    unsigned long long* __restrict__ rowb, unsigned long long* __restrict__ rowc,
    float* __restrict__ S, int zeroS)
{
    __shared__ __align__(16) char smem[131072];  // A: 2x32KB @0, B: 2x32KB @64KB

    const int tid  = threadIdx.x;
    const int lane = tid & 63;
    const int wave = tid >> 6;
    const int wm = wave >> 2, wn = wave & 3;     // 2M x 4N wave grid; 128x64 per wave
    const int c = lane & 15, quad = lane >> 4;

    const int o = blockIdx.x;
    const int xcd = o & 7, idx = o >> 3;
    const int ntile = (xcd << 3) | (idx & 7);
    const int mtile = idx >> 3;
    const int m0 = mtile * 256, n0 = ntile * 256;

    const _Float16* Abase = Ah + (size_t)m0 * D_;
    const _Float16* Wbase = Wh + (size_t)n0 * D_;

    const int i0 = tid, i1 = 512 + tid;
    const int rl0 = i0 >> 3, sl0 = i0 & 7, rl1 = i1 >> 3, sl1 = i1 & 7;
    const size_t srcoff0 = (size_t)rl0 * D_ + ((sl0 ^ (rl0 & 7)) << 3);
    const size_t srcoff1 = (size_t)rl1 * D_ + ((sl1 ^ (rl1 & 7)) << 3);
    const int ldsoff0 = i0 << 4, ldsoff1 = i1 << 4;

    const int sA = (wm * 128 + c) * 128;
    const int sB = (wn * 64 + c) * 128;
    const int swz0 = ((0 * 4 + quad) ^ (c & 7)) << 4;   // kk=0
    const int swz1 = ((1 * 4 + quad) ^ (c & 7)) << 4;   // kk=1

    f32x4 acc[8][4];
    #pragma unroll
    for (int i = 0; i < 8; i++)
        #pragma unroll
        for (int j = 0; j < 4; j++)
            acc[i][j] = (f32x4){0.f, 0.f, 0.f, 0.f};

    STAGE_HALF(Abase, 0, 0, 0);
    STAGE_HALF(Wbase, 65536, 0, 0);
    STAGE_HALF(Wbase, 65536, 0, 1);
    STAGE_HALF(Abase, 0, 0, 1);
    STAGE_HALF(Abase, 0, 1, 0);
    STAGE_HALF(Wbase, 65536, 1, 0);
    STAGE_HALF(Wbase, 65536, 1, 1);
    PH_WAIT(6); SBAR;

    TILE(0, 1, 1, 1, 1, 6);
    TILE(1, 1, 1, 1, 1, 6);
    TILE(2, 1, 1, 1, 1, 6);
    TILE(3, 1, 1, 1, 1, 6);
    TILE(4, 1, 1, 1, 1, 6);
    TILE(5, 1, 1, 1, 1, 6);
    TILE(6, 1, 0, 0, 1, 0);
    TILE(7, 0, 0, 0, 0, 0);

    __syncthreads();   // GEMM done; reuse smem as [256][64] u64 candidate table

    const unsigned long long ID = PKID_;
    float wnl[4]; int cll[4];
    #pragma unroll
    for (int ni = 0; ni < 4; ni++) {
        int n = n0 + wn * 64 + ni * 16 + c;
        wnl[ni] = wnorm[n];
        cll[ni] = clabels[n];
    }

    unsigned long long (*tbl)[64] = (unsigned long long (*)[64])smem;  // 128KB exactly
    unsigned long long cbst[8][4];

    #pragma unroll
    for (int mi = 0; mi < 8; mi++) {
        #pragma unroll
        for (int r = 0; r < 4; r++) {
            int rowl = wm * 128 + mi * 16 + quad * 4 + r;   // 0..255 in block
            int lb = labels[m0 + rowl];
            unsigned long long bb = ID, cb = ID;
            #pragma unroll
            for (int ni = 0; ni < 4; ni++) {
                float s = fmaf(-2.f, acc[mi][ni][r], wnl[ni]);
                unsigned long long pk = packmin(s, n0 + wn * 64 + ni * 16 + c);
                bb = bb < pk ? bb : pk;
                if (cll[ni] == lb) cb = cb < pk ? cb : pk;
            }
            tbl[rowl][(wn * 16 + c) ^ (rowl & 15)] = bb;   // XOR slot: caps conflicts 4-way
            cbst[mi][r] = cb;
        }
    }
    __syncthreads();
    if (tid < 256) {
        int row = tid;
        unsigned long long m = ID;
        #pragma unroll
        for (int j = 0; j < 64; j++) {
            unsigned long long v = tbl[row][j ^ (row & 15)];
            m = m < v ? m : v;
        }
        atomicMin(&rowb[m0 + row], m);   // packed lex-min: bit-identical to tree-min
    }
    __syncthreads();
    #pragma unroll
    for (int mi = 0; mi < 8; mi++)
        #pragma unroll
        for (int r = 0; r < 4; r++) {
            int rowl = wm * 128 + mi * 16 + quad * 4 + r;
            tbl[rowl][(wn * 16 + c) ^ (rowl & 15)] = cbst[mi][r];
        }
    __syncthreads();
    if (tid < 256) {
        int row = tid;
        unsigned long long m = ID;
        #pragma unroll
        for (int j = 0; j < 64; j++) {
            unsigned long long v = tbl[row][j ^ (row & 15)];
            m = m < v ? m : v;
        }
        atomicMin(&rowc[m0 + row], m);
    }

    // zero this block's 1/1024 slice of S (fused-S layout only; non-aliased).
    if (zeroS) {
        const float4 z = {0.f, 0.f, 0.f, 0.f};
        float4* Sz = (float4*)(S + (size_t)o * 8192);
        #pragma unroll
        for (int k = 0; k < 4; k++)
            Sz[k * 512 + tid] = z;
    }
}

// ---------------- reduce: wave-autonomous per row + scatter; W-gather skipped when sc==0 ----------------
// rel >= 0.95 holds for ~5% of class-BMUs (crel uniform [0,100]); sc==0 -> skip the
// wave-uniform W-row gather and store exact zeros (reference emits exact zeros too).
__global__ __launch_bounds__(256) void reduce_kernel(
    const float* __restrict__ A, const float* __restrict__ W,
    const float* __restrict__ crel,
    const unsigned long long* __restrict__ rowb,
    const unsigned long long* __restrict__ rowc,
    float* __restrict__ sum_min, float* __restrict__ out0,
    float* __restrict__ S, float* __restrict__ count)
{
    const int b = blockIdx.x * 4 + (threadIdx.x >> 6);
    const int l = threadIdx.x & 63;

    float bv; int bn; unpackmin(rowb[b], &bv, &bn);
    float cv; int cn; unpackmin(rowc[b], &cv, &cn);

    const float* arow = A + (size_t)b * D_;
    float4 xa = ((const float4*)arow)[l];
    float4 xb = ((const float4*)arow)[l + 64];
    float xs = xa.x*xa.x + xa.y*xa.y + xa.z*xa.z + xa.w*xa.w
             + xb.x*xb.x + xb.y*xb.y + xb.z*xb.z + xb.w*xb.w;
    #pragma unroll
    for (int off = 1; off < 64; off <<= 1) xs += __shfl_xor(xs, off, 64);

    if (l == 0) {
        float md = xs + bv;
        if (md < 0.f) md = 0.f;
        atomicAdd(&sum_min[b & 63], md);
        atomicAdd(&count[bn], 1.0f);
    }

    float* orow = out0 + (size_t)b * D_;
    float r = crel[cn] / 100.0f;          // cn wave-uniform -> uniform branch
    if (r >= THR_) {
        float sc = 0.01f * r;
        const float* wrow = W + (size_t)cn * D_;
        float4 wa = ((const float4*)wrow)[l];
        float4 wb = ((const float4*)wrow)[l + 64];
        float4 oa, ob4;
        oa.x = sc * (wa.x - xa.x); oa.y = sc * (wa.y - xa.y);
        oa.z = sc * (wa.z - xa.z); oa.w = sc * (wa.w - xa.w);
        ob4.x = sc * (wb.x - xb.x); ob4.y = sc * (wb.y - xb.y);
        ob4.z = sc * (wb.z - xb.z); ob4.w = sc * (wb.w - xb.w);
        ((float4*)orow)[l]      = oa;
        ((float4*)orow)[l + 64] = ob4;
    } else {
        const float4 z = {0.f, 0.f, 0.f, 0.f};
        ((float4*)orow)[l]      = z;
        ((float4*)orow)[l + 64] = z;
    }

    float* Sr = S + (size_t)bn * D_;
    #pragma unroll
    for (int k = 0; k < 8; k++)
        atomicAdd(&Sr[k * 64 + l], arow[k * 64 + l]);
}

// ---------------- final: out1 = som + stencil(S) - som*denom (gated); ctx-specialized ----------------
// Runtime ctx blocked loop unrolling (serial bounds-checked taps). ctx in {0,1,2} only;
// specialize ctx==1 (benchmark input) branchless: invalid taps use coef=0 at a clamped
// valid address — adding +-0 never changes an IEEE sum, tap order preserved -> bit-exact.
__global__ __launch_bounds__(256) void final_kernel(
    const float* __restrict__ som, const float* __restrict__ S,
    const float* __restrict__ count, const float* __restrict__ sum_min,
    const int* __restrict__ epoch_p, const int* __restrict__ maxep_p,
    float* __restrict__ out1)
{
    __shared__ float gsum;
    if (threadIdx.x < 64) {
        float s = sum_min[threadIdx.x];
        #pragma unroll
        for (int off = 32; off > 0; off >>= 1) s += __shfl_xor(s, off, 64);
        if (threadIdx.x == 0) gsum = s;
    }
    __syncthreads();

    const int o = blockIdx.x;                      // 8192 blocks
    const int vb = ((o & 7) << 10) | (o >> 3);     // xcd*1024 + idx  (bijective)
    size_t i4 = (size_t)vb * 256 + threadIdx.x;
    int n = (int)(i4 >> 7);          // 128 float4 per cell row
    int d4 = (int)(i4 & 127);
    float4 s = ((const float4*)som)[i4];
    bool gate = gsum > 1e-4f * (float)B_;   // mean(min_dists) > 1e-4
    float4 ov = s;
    if (gate) {
        int ep = epoch_p[0], me = maxep_p[0];
        float progress = (me > 0) ? (float)(me - ep) / (float)me : 0.f;
        progress = fminf(fmaxf(progress, 0.f), 1.f);
        float p2 = progress * progress;
        int ctx = (int)(p2 * p2 * 2.0f);
        float lr = 0.05f + progress * 0.15f;

        int i = n >> 7, j = n & (G_ - 1);
        float4 nu = {0.f, 0.f, 0.f, 0.f};
        float dn = 0.f;
        if (ctx == 1) {
            #pragma unroll
            for (int di = -1; di <= 1; di++) {
                #pragma unroll
                for (int dj = -1; dj <= 1; dj++) {
                    int ia = i - di, jb = j - dj;
                    bool ok = ((unsigned)ia < (unsigned)G_) && ((unsigned)jb < (unsigned)G_);
                    int iac = ok ? ia : i;
                    int jbc = ok ? jb : j;
                    int ad = di < 0 ? -di : di, aj = dj < 0 ? -dj : dj;
                    int cheb = ad > aj ? ad : aj;
                    float coef = ok ? ldexpf(lr, -cheb) : 0.f;
                    float4 t4 = ((const float4*)S)[(size_t)(jbc * G_ + iac) * 128 + d4];
                    nu.x += coef * t4.x; nu.y += coef * t4.y;
                    nu.z += coef * t4.z; nu.w += coef * t4.w;
                    dn += coef * count[jbc * G_ + iac];
                }
            }
        } else if (ctx == 0) {
            float4 t4 = ((const float4*)S)[(size_t)(j * G_ + i) * 128 + d4];
            nu.x = lr * t4.x; nu.y = lr * t4.y;
            nu.z = lr * t4.z; nu.w = lr * t4.w;
            dn = lr * count[j * G_ + i];
        } else {                                   // ctx == 2
            #pragma unroll
            for (int di = -2; di <= 2; di++) {
                #pragma unroll
                for (int dj = -2; dj <= 2; dj++) {
                    int ia = i - di, jb = j - dj;
                    bool ok = ((unsigned)ia < (unsigned)G_) && ((unsigned)jb < (unsigned)G_);
                    int iac = ok ? ia : i;
                    int jbc = ok ? jb : j;
                    int ad = di < 0 ? -di : di, aj = dj < 0 ? -dj : dj;
                    int cheb = ad > aj ? ad : aj;
                    float coef = ok ? ldexpf(lr, -cheb) : 0.f;
                    float4 t4 = ((const float4*)S)[(size_t)(jbc * G_ + iac) * 128 + d4];
                    nu.x += coef * t4.x; nu.y += coef * t4.y;
                    nu.z += coef * t4.z; nu.w += coef * t4.w;
                    dn += coef * count[jbc * G_ + iac];
                }
            }
        }
        ov.x = s.x + nu.x - s.x * dn;
        ov.y = s.y + nu.y - s.y * dn;
        ov.z = s.z + nu.z - s.z * dn;
        ov.w = s.w + nu.w - s.w * dn;
    }
    ((float4*)out1)[i4] = ov;
}

extern "C" void kernel_launch(void* const* d_in, const int* in_sizes, int n_in,
                              void* d_out, int out_size, void* d_ws, size_t ws_size,
                              hipStream_t stream) {
    const float* A   = (const float*)d_in[0];   // activations [B][D]
    const int*   lab = (const int*)d_in[1];     // labels [B]
    const float* W   = (const float*)d_in[2];   // som_vectors [G*G][D]
    const int*   cl  = (const int*)d_in[3];     // cell_labels [G*G]
    const float* cr  = (const float*)d_in[4];   // cell_reliability [G*G]
    const int*   ep  = (const int*)d_in[5];     // epoch
    const int*   me  = (const int*)d_in[6];     // max_epochs

    float* out0 = (float*)d_out;                // som_errors [B][D]
    float* out1 = out0 + (size_t)B_ * D_;       // new_som [G*G][D]

    const size_t MB = 1024 * 1024;
    uint8_t* w = (uint8_t*)d_ws;
    _Float16* Ahi  = (_Float16*)(w);                    //  4 MB
    _Float16* Whi  = (_Float16*)(w + 4 * MB);           // 16 MB
    unsigned long long* rowb = (unsigned long long*)(w + 32 * MB);   // 32 KB
    unsigned long long* rowc = (unsigned long long*)(w + 33 * MB);   // 32 KB
    float* wnorm   = (float*)(w + 40 * MB);             // 64 KB
    float* count   = (float*)(w + 40 * MB + 128 * 1024);// 64 KB
    float* sum_min = (float*)(w + 40 * MB + 256 * 1024);// 65 floats: 64 buckets + total

    // S: non-aliased at [48,80) MB if workspace allows (zeroed in score epilogue);
    // else aliases the dead f16 region and is zeroed by a stream-ordered memset.
    const int fusedS = (ws_size >= 80 * MB) ? 1 : 0;
    float* S = fusedS ? (float*)(w + 48 * MB) : (float*)w;

    prep_kernel<<<6162, 256, 0, stream>>>(A, W, Ahi, Whi, wnorm, count, sum_min,
                                          rowb, rowc);

    score_mfma_kernel<<<dim3((B_ / 256) * (N_ / 256)), 512, 0, stream>>>(
        Ahi, Whi, wnorm, lab, cl, rowb, rowc, S, fusedS);

    if (!fusedS)
        hipMemsetAsync(S, 0, (size_t)N_ * D_ * sizeof(float), stream);

    reduce_kernel<<<B_ / 4, 256, 0, stream>>>(A, W, cr, rowb, rowc,
                                              sum_min, out0, S, count);

    final_kernel<<<(N_ * D_ / 4) / 256, 256, 0, stream>>>(
        W, S, count, sum_min, ep, me, out1);
}